// Round 1
// baseline (144.296 us; speedup 1.0000x reference)
//
#include <hip/hip_runtime.h>
#include <math.h>

#define NSEG 20001      // I_DIM + 1 segments / items
#define EMB  128
#define NE   640000

__device__ __forceinline__ float dot4(float4 a, float4 b) {
    return a.x*b.x + a.y*b.y + a.z*b.z + a.w*b.w;
}

#define FMA4(acc, s, b) { acc.x += (s)*(b).x; acc.y += (s)*(b).y; acc.z += (s)*(b).z; acc.w += (s)*(b).w; }

// K1: item_scaled = emb @ W_scale + b_scale  (20001 x 128)
//     fused: a_src[i] = item_scaled[i] . W_att[0:128]
//            a_dst[i] = item_scaled[i] . W_att[128:256]
// Block: 256 threads = 32 col-groups (4 cols each) x 8 row-groups (2 rows each) -> 16 rows/block.
__global__ __launch_bounds__(256) void scale_kernel(
    const float* __restrict__ emb, const float* __restrict__ W,
    const float* __restrict__ bsc, const float* __restrict__ Watt,
    float* __restrict__ item_scaled, float* __restrict__ a_src, float* __restrict__ a_dst)
{
    __shared__ float emb_s[16 * EMB];   // 8 KB
    const int tid = threadIdx.x;
    const int r0  = blockIdx.x * 16;

    // stage 16 rows of emb into LDS (float4 coalesced, clamp OOB rows)
    const float4* embg4 = (const float4*)emb;
    float4* es4 = (float4*)emb_s;
    const int gmax = NSEG * 32 - 1;     // last valid float4 index in emb
    #pragma unroll
    for (int j = 0; j < 2; ++j) {
        int idx = tid + j * 256;        // 0..511 float4 slots in tile
        int g = r0 * 32 + idx;
        es4[idx] = embg4[g <= gmax ? g : gmax];
    }
    __syncthreads();

    const int cg = tid & 31;            // column group: cols [4cg, 4cg+4)
    const int rb = (tid >> 5) * 2;      // row base within tile (2 rows/thread)

    float4 acc0 = {0.f,0.f,0.f,0.f};
    float4 acc1 = {0.f,0.f,0.f,0.f};
    const float4* Wg4 = (const float4*)W;

    for (int k = 0; k < EMB; k += 4) {
        float4 b0 = Wg4[(k+0)*32 + cg];
        float4 b1 = Wg4[(k+1)*32 + cg];
        float4 b2 = Wg4[(k+2)*32 + cg];
        float4 b3 = Wg4[(k+3)*32 + cg];
        float4 a0 = *(const float4*)&emb_s[(rb+0)*EMB + k];
        float4 a1 = *(const float4*)&emb_s[(rb+1)*EMB + k];
        FMA4(acc0, a0.x, b0); FMA4(acc0, a0.y, b1); FMA4(acc0, a0.z, b2); FMA4(acc0, a0.w, b3);
        FMA4(acc1, a1.x, b0); FMA4(acc1, a1.y, b1); FMA4(acc1, a1.z, b2); FMA4(acc1, a1.w, b3);
    }

    float4 bs = *(const float4*)&bsc[cg*4];
    acc0.x += bs.x; acc0.y += bs.y; acc0.z += bs.z; acc0.w += bs.w;
    acc1.x += bs.x; acc1.y += bs.y; acc1.z += bs.z; acc1.w += bs.w;

    const int row0 = r0 + rb;
    const int row1 = row0 + 1;
    if (row0 < NSEG) *(float4*)&item_scaled[row0*EMB + cg*4] = acc0;
    if (row1 < NSEG) *(float4*)&item_scaled[row1*EMB + cg*4] = acc1;

    // fused a_src / a_dst: dot with W_att halves, reduce over 32 col-groups
    float4 ws = *(const float4*)&Watt[cg*4];
    float4 wd = *(const float4*)&Watt[EMB + cg*4];
    float p0s = dot4(acc0, ws), p0d = dot4(acc0, wd);
    float p1s = dot4(acc1, ws), p1d = dot4(acc1, wd);
    #pragma unroll
    for (int off = 16; off >= 1; off >>= 1) {
        p0s += __shfl_xor(p0s, off);
        p0d += __shfl_xor(p0d, off);
        p1s += __shfl_xor(p1s, off);
        p1d += __shfl_xor(p1d, off);
    }
    if ((tid & 31) == 0) {
        if (row0 < NSEG) { a_src[row0] = p0s; a_dst[row0] = p0d; }
        if (row1 < NSEG) { a_src[row1] = p1s; a_dst[row1] = p1d; }
    }
}

// K2: segment boundaries from the sorted edge[:,0] column.
// seg_start[t] = first edge index whose seg >= t;  seg_start[NSEG] = NE.
__global__ __launch_bounds__(256) void bounds_kernel(
    const int* __restrict__ edge, int* __restrict__ seg_start)
{
    int e = blockIdx.x * 256 + threadIdx.x;
    if (e >= NE) return;
    int s  = edge[2*e];
    int sp = (e == 0) ? -1 : edge[2*e - 2];
    for (int t = sp + 1; t <= s; ++t) seg_start[t] = e;
    if (e == NE - 1) {
        for (int t = s + 1; t <= NSEG; ++t) seg_start[t] = NE;
    }
}

// K3: one wave per segment. Lane l owns output features {2l, 2l+1}.
// Per 64-edge chunk: each lane computes the score for its own edge, then the
// wave iterates the chunk's edges broadcasting (score, dst) via readlane and
// doing a coalesced float2 gather of item_scaled[dst]. Normalize + sigmoid at end.
__global__ __launch_bounds__(256) void agg_kernel(
    const int* __restrict__ edge, const float* __restrict__ a_src,
    const float* __restrict__ a_dst, const float* __restrict__ b_att,
    const int* __restrict__ seg_start, const float* __restrict__ item_scaled,
    float* __restrict__ out)
{
    const int wid = blockIdx.x * 4 + (threadIdx.x >> 6);
    if (wid >= NSEG) return;                 // wave-uniform exit
    const int lane = threadIdx.x & 63;

    const int s0 = seg_start[wid];
    const int s1 = seg_start[wid + 1];
    const float aS = a_src[wid] + b_att[0];

    float accx = 0.f, accy = 0.f, ssum = 0.f;

    for (int cb = s0; cb < s1; cb += 64) {
        int n = s1 - cb; if (n > 64) n = 64;
        int e = cb + lane;
        int dmine = 0; float sc = 0.f;
        if (lane < n) {
            dmine = edge[2*e + 1];
            float att = aS + a_dst[dmine];
            att = att > 0.f ? att : 0.2f * att;   // leaky_relu 0.2
            sc  = expf(att - 1.f);
        }
        ssum += sc;
        for (int j = 0; j < n; ++j) {
            float w  = __uint_as_float(__builtin_amdgcn_readlane(__float_as_uint(sc), j));
            int   dj = __builtin_amdgcn_readlane(dmine, j);
            const float2 v = *(const float2*)&item_scaled[dj * EMB + 2 * lane];
            accx += w * v.x;
            accy += w * v.y;
        }
    }

    #pragma unroll
    for (int off = 32; off >= 1; off >>= 1) ssum += __shfl_xor(ssum, off);

    const float inv = (s1 > s0) ? 1.f / ssum : 0.f;
    float ox = accx * inv, oy = accy * inv;
    ox = 1.f / (1.f + expf(-ox));
    oy = 1.f / (1.f + expf(-oy));
    *(float2*)&out[wid * EMB + 2 * lane] = make_float2(ox, oy);
}

extern "C" void kernel_launch(void* const* d_in, const int* in_sizes, int n_in,
                              void* d_out, int out_size, void* d_ws, size_t ws_size,
                              hipStream_t stream) {
    const float* emb  = (const float*)d_in[0];   // (20001, 128)
    const int*   edge = (const int*)  d_in[1];   // (640000, 2)
    const float* W    = (const float*)d_in[2];   // (128, 128)
    const float* bsc  = (const float*)d_in[3];   // (128,)
    const float* Watt = (const float*)d_in[4];   // (256,)
    const float* batt = (const float*)d_in[5];   // (1,)
    float* out = (float*)d_out;                  // (20001, 128)

    float* item_scaled = (float*)d_ws;                  // NSEG*EMB floats
    float* a_src = item_scaled + (size_t)NSEG * EMB;    // NSEG
    float* a_dst = a_src + NSEG;                        // NSEG
    int*   seg_start = (int*)(a_dst + NSEG);            // NSEG+1

    scale_kernel<<<(NSEG + 15) / 16, 256, 0, stream>>>(emb, W, bsc, Watt,
                                                       item_scaled, a_src, a_dst);
    bounds_kernel<<<(NE + 255) / 256, 256, 0, stream>>>(edge, seg_start);
    agg_kernel<<<(NSEG + 3) / 4, 256, 0, stream>>>(edge, a_src, a_dst, batt,
                                                   seg_start, item_scaled, out);
}

// Round 2
// 116.125 us; speedup vs baseline: 1.2426x; 1.2426x over previous
//
#include <hip/hip_runtime.h>
#include <math.h>

#define NSEG 20001      // I_DIM + 1 segments / items
#define EMB  128
#define NE   640000

#define SCALE_BLOCKS ((NSEG + 15) / 16)          // 1251
#define BOUNDS_BLOCKS ((NE + 255) / 256)         // 2500

__device__ __forceinline__ float dot4(float4 a, float4 b) {
    return a.x*b.x + a.y*b.y + a.z*b.z + a.w*b.w;
}

#define FMA4(acc, s, b) { acc.x += (s)*(b).x; acc.y += (s)*(b).y; acc.z += (s)*(b).z; acc.w += (s)*(b).w; }

__device__ __forceinline__ unsigned short f2bf(float x) {
    unsigned u = __float_as_uint(x);
    unsigned r = (u + 0x7fffu + ((u >> 16) & 1u)) >> 16;   // round-nearest-even
    return (unsigned short)r;
}

// Fused prep: blocks [0, SCALE_BLOCKS) do item_scaled(bf16) + a_src/a_dst;
// blocks [SCALE_BLOCKS, +BOUNDS_BLOCKS) do segment boundary detection.
__global__ __launch_bounds__(256) void prep_kernel(
    const float* __restrict__ emb, const float* __restrict__ W,
    const float* __restrict__ bsc, const float* __restrict__ Watt,
    const int* __restrict__ edge,
    unsigned short* __restrict__ tab,       // bf16 item_scaled, NSEG x EMB
    float* __restrict__ a_src, float* __restrict__ a_dst,
    int* __restrict__ seg_start)
{
    const int tid = threadIdx.x;
    if (blockIdx.x >= SCALE_BLOCKS) {
        // ---- bounds branch ----
        int e = (blockIdx.x - SCALE_BLOCKS) * 256 + tid;
        if (e >= NE) return;
        int s  = edge[2*e];
        int sp = (e == 0) ? -1 : edge[2*e - 2];
        for (int t = sp + 1; t <= s; ++t) seg_start[t] = e;
        if (e == NE - 1) {
            for (int t = s + 1; t <= NSEG; ++t) seg_start[t] = NE;
        }
        return;
    }

    // ---- scale branch: 16 rows/block, thread = (col-group cg: 4 cols) x (2 rows) ----
    __shared__ float emb_s[16 * EMB];   // 8 KB
    const int r0 = blockIdx.x * 16;

    const float4* embg4 = (const float4*)emb;
    float4* es4 = (float4*)emb_s;
    const int gmax = NSEG * 32 - 1;
    #pragma unroll
    for (int j = 0; j < 2; ++j) {
        int idx = tid + j * 256;
        int g = r0 * 32 + idx;
        es4[idx] = embg4[g <= gmax ? g : gmax];
    }
    __syncthreads();

    const int cg = tid & 31;
    const int rb = (tid >> 5) * 2;

    float4 acc0 = {0.f,0.f,0.f,0.f};
    float4 acc1 = {0.f,0.f,0.f,0.f};
    const float4* Wg4 = (const float4*)W;

    for (int k = 0; k < EMB; k += 4) {
        float4 b0 = Wg4[(k+0)*32 + cg];
        float4 b1 = Wg4[(k+1)*32 + cg];
        float4 b2 = Wg4[(k+2)*32 + cg];
        float4 b3 = Wg4[(k+3)*32 + cg];
        float4 a0 = *(const float4*)&emb_s[(rb+0)*EMB + k];
        float4 a1 = *(const float4*)&emb_s[(rb+1)*EMB + k];
        FMA4(acc0, a0.x, b0); FMA4(acc0, a0.y, b1); FMA4(acc0, a0.z, b2); FMA4(acc0, a0.w, b3);
        FMA4(acc1, a1.x, b0); FMA4(acc1, a1.y, b1); FMA4(acc1, a1.z, b2); FMA4(acc1, a1.w, b3);
    }

    float4 bs = *(const float4*)&bsc[cg*4];
    acc0.x += bs.x; acc0.y += bs.y; acc0.z += bs.z; acc0.w += bs.w;
    acc1.x += bs.x; acc1.y += bs.y; acc1.z += bs.z; acc1.w += bs.w;

    const int row0 = r0 + rb;
    const int row1 = row0 + 1;
    if (row0 < NSEG) {
        ushort4 p = { f2bf(acc0.x), f2bf(acc0.y), f2bf(acc0.z), f2bf(acc0.w) };
        *(ushort4*)&tab[row0*EMB + cg*4] = p;
    }
    if (row1 < NSEG) {
        ushort4 p = { f2bf(acc1.x), f2bf(acc1.y), f2bf(acc1.z), f2bf(acc1.w) };
        *(ushort4*)&tab[row1*EMB + cg*4] = p;
    }

    // fused a_src / a_dst (fp32 accs, fp32 W_att)
    float4 ws = *(const float4*)&Watt[cg*4];
    float4 wd = *(const float4*)&Watt[EMB + cg*4];
    float p0s = dot4(acc0, ws), p0d = dot4(acc0, wd);
    float p1s = dot4(acc1, ws), p1d = dot4(acc1, wd);
    #pragma unroll
    for (int off = 16; off >= 1; off >>= 1) {
        p0s += __shfl_xor(p0s, off);
        p0d += __shfl_xor(p0d, off);
        p1s += __shfl_xor(p1s, off);
        p1d += __shfl_xor(p1d, off);
    }
    if ((tid & 31) == 0) {
        if (row0 < NSEG) { a_src[row0] = p0s; a_dst[row0] = p0d; }
        if (row1 < NSEG) { a_src[row1] = p1s; a_dst[row1] = p1d; }
    }
}

__device__ __forceinline__ float bcastf(float v, int j) {
    return __uint_as_float(__builtin_amdgcn_readlane(__float_as_uint(v), j));
}
__device__ __forceinline__ float bf_lo(unsigned u) { return __uint_as_float(u << 16); }
__device__ __forceinline__ float bf_hi(unsigned u) { return __uint_as_float(u & 0xffff0000u); }

// agg: one wave per segment; lane l owns features {2l, 2l+1} (one bf16x2 dword).
__global__ __launch_bounds__(256) void agg_kernel(
    const int* __restrict__ edge, const float* __restrict__ a_src,
    const float* __restrict__ a_dst, const float* __restrict__ b_att,
    const int* __restrict__ seg_start, const unsigned int* __restrict__ tab32,
    float* __restrict__ out)
{
    const int wid = blockIdx.x * 4 + (threadIdx.x >> 6);
    if (wid >= NSEG) return;                 // wave-uniform exit
    const int lane = threadIdx.x & 63;
    const unsigned int* tabl = tab32 + lane; // row stride 64 dwords

    const int s0 = seg_start[wid];
    const int s1 = seg_start[wid + 1];
    const float aS = a_src[wid] + b_att[0];

    float accx = 0.f, accy = 0.f, ssum = 0.f;

    for (int cb = s0; cb < s1; cb += 64) {
        int n = s1 - cb; if (n > 64) n = 64;
        int e = cb + lane;
        int dmine = 0; float sc = 0.f;
        if (lane < n) {
            dmine = edge[2*e + 1] << 6;      // pre-scale to dword row offset
            float att = aS + a_dst[dmine >> 6];
            att = att > 0.f ? att : 0.2f * att;   // leaky_relu 0.2
            sc  = expf(att - 1.f);
        }
        ssum += sc;

        int j = 0;
        for (; j + 3 < n; j += 4) {
            float w0 = bcastf(sc, j+0), w1 = bcastf(sc, j+1);
            float w2 = bcastf(sc, j+2), w3 = bcastf(sc, j+3);
            int d0 = __builtin_amdgcn_readlane(dmine, j+0);
            int d1 = __builtin_amdgcn_readlane(dmine, j+1);
            int d2 = __builtin_amdgcn_readlane(dmine, j+2);
            int d3 = __builtin_amdgcn_readlane(dmine, j+3);
            unsigned u0 = tabl[d0];
            unsigned u1 = tabl[d1];
            unsigned u2 = tabl[d2];
            unsigned u3 = tabl[d3];
            accx += w0 * bf_lo(u0); accy += w0 * bf_hi(u0);
            accx += w1 * bf_lo(u1); accy += w1 * bf_hi(u1);
            accx += w2 * bf_lo(u2); accy += w2 * bf_hi(u2);
            accx += w3 * bf_lo(u3); accy += w3 * bf_hi(u3);
        }
        for (; j < n; ++j) {
            float w = bcastf(sc, j);
            int   d = __builtin_amdgcn_readlane(dmine, j);
            unsigned u = tabl[d];
            accx += w * bf_lo(u);
            accy += w * bf_hi(u);
        }
    }

    #pragma unroll
    for (int off = 32; off >= 1; off >>= 1) ssum += __shfl_xor(ssum, off);

    const float inv = (s1 > s0) ? 1.f / ssum : 0.f;
    float ox = accx * inv, oy = accy * inv;
    ox = 1.f / (1.f + expf(-ox));
    oy = 1.f / (1.f + expf(-oy));
    *(float2*)&out[wid * EMB + 2 * lane] = make_float2(ox, oy);
}

extern "C" void kernel_launch(void* const* d_in, const int* in_sizes, int n_in,
                              void* d_out, int out_size, void* d_ws, size_t ws_size,
                              hipStream_t stream) {
    const float* emb  = (const float*)d_in[0];   // (20001, 128)
    const int*   edge = (const int*)  d_in[1];   // (640000, 2)
    const float* W    = (const float*)d_in[2];   // (128, 128)
    const float* bsc  = (const float*)d_in[3];   // (128,)
    const float* Watt = (const float*)d_in[4];   // (256,)
    const float* batt = (const float*)d_in[5];   // (1,)
    float* out = (float*)d_out;                  // (20001, 128)

    unsigned short* tab = (unsigned short*)d_ws;            // NSEG*EMB bf16
    float* a_src = (float*)(tab + (size_t)NSEG * EMB);      // NSEG
    float* a_dst = a_src + NSEG;                            // NSEG
    int*   seg_start = (int*)(a_dst + NSEG);                // NSEG+1

    prep_kernel<<<SCALE_BLOCKS + BOUNDS_BLOCKS, 256, 0, stream>>>(
        emb, W, bsc, Watt, edge, tab, a_src, a_dst, seg_start);
    agg_kernel<<<(NSEG + 3) / 4, 256, 0, stream>>>(
        edge, a_src, a_dst, batt, seg_start, (const unsigned int*)tab, out);
}